// Round 4
// baseline (110.186 us; speedup 1.0000x reference)
//
#include <hip/hip_runtime.h>

#define BATCH   2048
#define IN_DIM  16384
#define OUT_DIM 16384
#define NGATES  16
#define ROWS_PER_BLOCK 8
#define NBLK (BATCH / ROWS_PER_BLOCK)   // 256 blocks = 1 per CU

typedef float f32x4 __attribute__((ext_vector_type(4)));

// COEFF[16][4] from the reference, hard-coded.
__constant__ float c_coeff[NGATES][4] = {
    {0, 0, 0, 0},  {0, 0, 0, 1},  {0, 1, 0, -1}, {0, 1, 0, 0},
    {0, 0, 1, -1}, {0, 0, 1, 0},  {0, 1, 1, -2}, {0, 1, 1, -1},
    {1, -1, -1, 1},{1, -1, -1, 2},{1, 0, -1, 0}, {1, 0, -1, 1},
    {1, -1, 0, 0}, {1, -1, 0, 1}, {1, 0, 0, -1}, {1, 0, 0, 0}
};

// Kernel 1: per output column j, fold softmax(weights[j,:]) @ COEFF into W[j]
// (float4) and pack both gather indices into one uint32 (ia | ib<<16).
__global__ __launch_bounds__(256) void prep_kernel(
    const float* __restrict__ weights,
    const int*   __restrict__ idx_a,
    const int*   __restrict__ idx_b,
    float4*      __restrict__ Wp,
    unsigned*    __restrict__ Ipk)
{
    int j = blockIdx.x * blockDim.x + threadIdx.x;
    if (j >= OUT_DIM) return;

    const float4* wrow = reinterpret_cast<const float4*>(weights + (size_t)j * NGATES);
    float v[NGATES];
    float4 q0 = wrow[0], q1 = wrow[1], q2 = wrow[2], q3 = wrow[3];
    v[0]=q0.x; v[1]=q0.y; v[2]=q0.z; v[3]=q0.w;
    v[4]=q1.x; v[5]=q1.y; v[6]=q1.z; v[7]=q1.w;
    v[8]=q2.x; v[9]=q2.y; v[10]=q2.z; v[11]=q2.w;
    v[12]=q3.x; v[13]=q3.y; v[14]=q3.z; v[15]=q3.w;

    float m = v[0];
#pragma unroll
    for (int g = 1; g < NGATES; ++g) m = fmaxf(m, v[g]);
    float s = 0.f;
#pragma unroll
    for (int g = 0; g < NGATES; ++g) { v[g] = expf(v[g] - m); s += v[g]; }
    float inv = 1.0f / s;

    float c0 = 0.f, c1 = 0.f, c2 = 0.f, c3 = 0.f;
#pragma unroll
    for (int g = 0; g < NGATES; ++g) {
        c0 += v[g] * c_coeff[g][0];
        c1 += v[g] * c_coeff[g][1];
        c2 += v[g] * c_coeff[g][2];
        c3 += v[g] * c_coeff[g][3];
    }
    Wp[j] = make_float4(c0 * inv, c1 * inv, c2 * inv, c3 * inv);
    Ipk[j] = (unsigned)idx_a[j] | ((unsigned)idx_b[j] << 16);   // both < 16384
}

// Async global->LDS stage of one 64 KB row: 4 rounds x 1024 threads x 16 B.
// Per wave the LDS dest is uniform-base + lane*16 (contiguous), matching the
// global_load_lds constraint.
__device__ __forceinline__ void stage_row(const float* __restrict__ xrow,
                                          float* lbuf, int tid)
{
#pragma unroll
    for (int kk = 0; kk < 4; ++kk) {
        __builtin_amdgcn_global_load_lds(
            (const __attribute__((address_space(1))) void*)(xrow + tid * 4 + kk * 4096),
            (__attribute__((address_space(3))) void*)(lbuf + tid * 4 + kk * 4096),
            16, 0, 0);
    }
}

// Kernel 2: 256 blocks (1/CU) x 1024 threads, 8 rows per block.
// W (16 x float4) and packed idx (4 x uint4) are row-invariant -> held in
// registers for the whole kernel; the row loop has NO global loads except the
// async stage of the next row (double-buffered 2x64 KB LDS). Counted
// vmcnt(4) + raw s_barrier per row keeps the next stage in flight under the
// current compute without ever draining the store queue.
__global__ __launch_bounds__(1024, 4) void logic_row_kernel(
    const float*  __restrict__ x,
    const float4* __restrict__ Wp,
    const uint4*  __restrict__ Ipk4,
    float*        __restrict__ out)
{
    __shared__ float buf[2][IN_DIM];   // 128 KB -> 1 block/CU
    const int tid  = threadIdx.x;
    const int row0 = blockIdx.x * ROWS_PER_BLOCK;

    // Hoist all row-invariant W / idx into registers (static indexing only).
    uint4  ii[4];
    float4 w[4][4];
#pragma unroll
    for (int k = 0; k < 4; ++k) {
        ii[k] = Ipk4[tid + k * 1024];
#pragma unroll
        for (int q = 0; q < 4; ++q)
            w[k][q] = Wp[(tid + k * 1024) * 4 + q];
    }

    // Prologue: stage row 0, full drain once.
    stage_row(x + (size_t)row0 * IN_DIM, buf[0], tid);
    __syncthreads();

    for (int r = 0; r < ROWS_PER_BLOCK; ++r) {
        // Issue next row's stage first so it streams under this row's compute.
        if (r + 1 < ROWS_PER_BLOCK) {
            stage_row(x + (size_t)(row0 + r + 1) * IN_DIM, buf[(r + 1) & 1], tid);
            // Pin issue order: stage loads must precede this iter's stores in
            // the VMEM queue so vmcnt(4) below provably covers the stage.
            __builtin_amdgcn_sched_barrier(0);
        }

        const float* __restrict__ rowbuf = buf[r & 1];
        f32x4* o4 = reinterpret_cast<f32x4*>(out + (size_t)(row0 + r) * OUT_DIM);

#pragma unroll
        for (int k = 0; k < 4; ++k) {
            uint4 q = ii[k];
            float a0 = rowbuf[q.x & 0xFFFFu], b0 = rowbuf[q.x >> 16];
            float a1 = rowbuf[q.y & 0xFFFFu], b1 = rowbuf[q.y >> 16];
            float a2 = rowbuf[q.z & 0xFFFFu], b2 = rowbuf[q.z >> 16];
            float a3 = rowbuf[q.w & 0xFFFFu], b3 = rowbuf[q.w >> 16];

            f32x4 res;
            res.x = w[k][0].x + w[k][0].y * a0 + w[k][0].z * b0 + w[k][0].w * (a0 * b0);
            res.y = w[k][1].x + w[k][1].y * a1 + w[k][1].z * b1 + w[k][1].w * (a1 * b1);
            res.z = w[k][2].x + w[k][2].y * a2 + w[k][2].z * b2 + w[k][2].w * (a2 * b2);
            res.w = w[k][3].x + w[k][3].y * a3 + w[k][3].z * b3 + w[k][3].w * (a3 * b3);
            __builtin_nontemporal_store(res, &o4[tid + k * 1024]);
        }

        if (r + 1 < ROWS_PER_BLOCK) {
            // Newest 4 VMEM ops are this iter's 4 NT stores -> vmcnt(4)
            // guarantees the 4 stage loads (and all older stores) retired.
            asm volatile("s_waitcnt vmcnt(4)" ::: "memory");
            __builtin_amdgcn_s_barrier();
        }
    }
}

extern "C" void kernel_launch(void* const* d_in, const int* in_sizes, int n_in,
                              void* d_out, int out_size, void* d_ws, size_t ws_size,
                              hipStream_t stream) {
    const float* x       = (const float*)d_in[0];
    const float* weights = (const float*)d_in[1];
    const int*   idx_a   = (const int*)d_in[2];
    const int*   idx_b   = (const int*)d_in[3];
    float* out = (float*)d_out;

    // Workspace layout: Wp (OUT_DIM float4 = 256 KB), Ipk (OUT_DIM uint = 64 KB)
    float4*   Wp  = (float4*)d_ws;
    unsigned* Ipk = (unsigned*)((char*)d_ws + (size_t)OUT_DIM * sizeof(float4));

    prep_kernel<<<(OUT_DIM + 255) / 256, 256, 0, stream>>>(weights, idx_a, idx_b, Wp, Ipk);
    logic_row_kernel<<<NBLK, 1024, 0, stream>>>(x, Wp, (const uint4*)Ipk, out);
}

// Round 5
// 105.186 us; speedup vs baseline: 1.0475x; 1.0475x over previous
//
#include <hip/hip_runtime.h>

#define BATCH   2048
#define IN_DIM  16384
#define OUT_DIM 16384
#define NGATES  16
#define ROWS_PER_BLOCK 4
#define NBLK (BATCH / ROWS_PER_BLOCK)   // 512 blocks = exactly 2 per CU

typedef float    f32x4 __attribute__((ext_vector_type(4)));
typedef _Float16 f16x4 __attribute__((ext_vector_type(4)));

// COEFF[16][4] from the reference, hard-coded.
__constant__ float c_coeff[NGATES][4] = {
    {0, 0, 0, 0},  {0, 0, 0, 1},  {0, 1, 0, -1}, {0, 1, 0, 0},
    {0, 0, 1, -1}, {0, 0, 1, 0},  {0, 1, 1, -2}, {0, 1, 1, -1},
    {1, -1, -1, 1},{1, -1, -1, 2},{1, 0, -1, 0}, {1, 0, -1, 1},
    {1, -1, 0, 0}, {1, -1, 0, 1}, {1, 0, 0, -1}, {1, 0, 0, 0}
};

// Kernel 1: per output column j, fold softmax(weights[j,:]) @ COEFF into
// W[j] stored as f16x4 (8 B), and pack gather indices into one uint32.
__global__ __launch_bounds__(256) void prep_kernel(
    const float* __restrict__ weights,
    const int*   __restrict__ idx_a,
    const int*   __restrict__ idx_b,
    f16x4*       __restrict__ Wh,
    unsigned*    __restrict__ Ipk)
{
    int j = blockIdx.x * blockDim.x + threadIdx.x;
    if (j >= OUT_DIM) return;

    const float4* wrow = reinterpret_cast<const float4*>(weights + (size_t)j * NGATES);
    float v[NGATES];
    float4 q0 = wrow[0], q1 = wrow[1], q2 = wrow[2], q3 = wrow[3];
    v[0]=q0.x; v[1]=q0.y; v[2]=q0.z; v[3]=q0.w;
    v[4]=q1.x; v[5]=q1.y; v[6]=q1.z; v[7]=q1.w;
    v[8]=q2.x; v[9]=q2.y; v[10]=q2.z; v[11]=q2.w;
    v[12]=q3.x; v[13]=q3.y; v[14]=q3.z; v[15]=q3.w;

    float m = v[0];
#pragma unroll
    for (int g = 1; g < NGATES; ++g) m = fmaxf(m, v[g]);
    float s = 0.f;
#pragma unroll
    for (int g = 0; g < NGATES; ++g) { v[g] = expf(v[g] - m); s += v[g]; }
    float inv = 1.0f / s;

    float c0 = 0.f, c1 = 0.f, c2 = 0.f, c3 = 0.f;
#pragma unroll
    for (int g = 0; g < NGATES; ++g) {
        c0 += v[g] * c_coeff[g][0];
        c1 += v[g] * c_coeff[g][1];
        c2 += v[g] * c_coeff[g][2];
        c3 += v[g] * c_coeff[g][3];
    }
    f16x4 h;
    h.x = (_Float16)(c0 * inv); h.y = (_Float16)(c1 * inv);
    h.z = (_Float16)(c2 * inv); h.w = (_Float16)(c3 * inv);
    Wh[j] = h;
    Ipk[j] = (unsigned)idx_a[j] | ((unsigned)idx_b[j] << 16);   // both < 16384
}

// Kernel 2: 512 blocks x 1024 threads, 4 rows per block, single 64 KB LDS
// buffer (2 blocks/CU resident). Next row is prefetched into REGISTERS while
// the current row computes (HBM fetch overlaps compute); after the compute
// barrier the registers are ds_written. W is f16x4 so the per-output L2
// stream is 12 B instead of 20 B. NT stores stream `out` past L2/L3.
__global__ __launch_bounds__(1024, 8) void logic_row_kernel(
    const float* __restrict__ x,
    const f16x4* __restrict__ Wh,
    const uint4* __restrict__ Ipk4,
    float*       __restrict__ out)
{
    __shared__ float row[IN_DIM];   // 64 KB
    const int tid  = threadIdx.x;
    const int row0 = blockIdx.x * ROWS_PER_BLOCK;

    f32x4* rw = reinterpret_cast<f32x4*>(row);
    f32x4  pf[4];

    // Prologue: load row 0 into registers, write to LDS.
    {
        const f32x4* xr = reinterpret_cast<const f32x4*>(x + (size_t)row0 * IN_DIM);
#pragma unroll
        for (int kk = 0; kk < 4; ++kk) pf[kk] = xr[tid + kk * 1024];
#pragma unroll
        for (int kk = 0; kk < 4; ++kk) rw[tid + kk * 1024] = pf[kk];
    }

    for (int r = 0; r < ROWS_PER_BLOCK; ++r) {
        __syncthreads();   // row r visible in LDS to all waves

        // Issue next row's global loads now; they stream under this row's
        // compute and are only consumed after the post-compute barrier.
        if (r + 1 < ROWS_PER_BLOCK) {
            const f32x4* xn = reinterpret_cast<const f32x4*>(
                x + (size_t)(row0 + r + 1) * IN_DIM);
#pragma unroll
            for (int kk = 0; kk < 4; ++kk) pf[kk] = xn[tid + kk * 1024];
        }

        f32x4* o4 = reinterpret_cast<f32x4*>(out + (size_t)(row0 + r) * OUT_DIM);

#pragma unroll
        for (int k = 0; k < 4; ++k) {
            const int j4 = tid + k * 1024;
            uint4 q = Ipk4[j4];
            const f16x4* wp = Wh + (size_t)j4 * 4;
            f16x4 w0 = wp[0], w1 = wp[1], w2 = wp[2], w3 = wp[3];

            float a0 = row[q.x & 0xFFFFu], b0 = row[q.x >> 16];
            float a1 = row[q.y & 0xFFFFu], b1 = row[q.y >> 16];
            float a2 = row[q.z & 0xFFFFu], b2 = row[q.z >> 16];
            float a3 = row[q.w & 0xFFFFu], b3 = row[q.w >> 16];

            f32x4 res;
            res.x = (float)w0.x + (float)w0.y * a0 + (float)w0.z * b0 + (float)w0.w * (a0 * b0);
            res.y = (float)w1.x + (float)w1.y * a1 + (float)w1.z * b1 + (float)w1.w * (a1 * b1);
            res.z = (float)w2.x + (float)w2.y * a2 + (float)w2.z * b2 + (float)w2.w * (a2 * b2);
            res.w = (float)w3.x + (float)w3.y * a3 + (float)w3.z * b3 + (float)w3.w * (a3 * b3);
            __builtin_nontemporal_store(res, &o4[j4]);
        }

        __syncthreads();   // all LDS reads of row r done
        if (r + 1 < ROWS_PER_BLOCK) {
#pragma unroll
            for (int kk = 0; kk < 4; ++kk) rw[tid + kk * 1024] = pf[kk];
        }
    }
}

extern "C" void kernel_launch(void* const* d_in, const int* in_sizes, int n_in,
                              void* d_out, int out_size, void* d_ws, size_t ws_size,
                              hipStream_t stream) {
    const float* x       = (const float*)d_in[0];
    const float* weights = (const float*)d_in[1];
    const int*   idx_a   = (const int*)d_in[2];
    const int*   idx_b   = (const int*)d_in[3];
    float* out = (float*)d_out;

    // Workspace layout: Wh (OUT_DIM f16x4 = 128 KB), Ipk (OUT_DIM uint = 64 KB)
    f16x4*    Wh  = (f16x4*)d_ws;
    unsigned* Ipk = (unsigned*)((char*)d_ws + (size_t)OUT_DIM * sizeof(f16x4));

    prep_kernel<<<(OUT_DIM + 255) / 256, 256, 0, stream>>>(weights, idx_a, idx_b, Wh, Ipk);
    logic_row_kernel<<<NBLK, 1024, 0, stream>>>(x, Wh, (const uint4*)Ipk, out);
}

// Round 6
// 56.264 us; speedup vs baseline: 1.9584x; 1.8695x over previous
//
#include <hip/hip_runtime.h>

#define BATCH   2048
#define IN_DIM  16384
#define OUT_DIM 16384
#define NGATES  16

typedef float    f32x4 __attribute__((ext_vector_type(4)));
typedef _Float16 f16x4 __attribute__((ext_vector_type(4)));
typedef _Float16 f16x8 __attribute__((ext_vector_type(8)));

// COEFF[16][4] from the reference, hard-coded.
__constant__ float c_coeff[NGATES][4] = {
    {0, 0, 0, 0},  {0, 0, 0, 1},  {0, 1, 0, -1}, {0, 1, 0, 0},
    {0, 0, 1, -1}, {0, 0, 1, 0},  {0, 1, 1, -2}, {0, 1, 1, -1},
    {1, -1, -1, 1},{1, -1, -1, 2},{1, 0, -1, 0}, {1, 0, -1, 1},
    {1, -1, 0, 0}, {1, -1, 0, 1}, {1, 0, 0, -1}, {1, 0, 0, 0}
};

// Kernel 1: per output column j, fold softmax(weights[j,:]) @ COEFF into
// W[j] stored as f16x4 (8 B), and pack gather indices into one uint32.
__global__ __launch_bounds__(256) void prep_kernel(
    const float* __restrict__ weights,
    const int*   __restrict__ idx_a,
    const int*   __restrict__ idx_b,
    f16x4*       __restrict__ Wh,
    unsigned*    __restrict__ Ipk)
{
    int j = blockIdx.x * blockDim.x + threadIdx.x;
    if (j >= OUT_DIM) return;

    const float4* wrow = reinterpret_cast<const float4*>(weights + (size_t)j * NGATES);
    float v[NGATES];
    float4 q0 = wrow[0], q1 = wrow[1], q2 = wrow[2], q3 = wrow[3];
    v[0]=q0.x; v[1]=q0.y; v[2]=q0.z; v[3]=q0.w;
    v[4]=q1.x; v[5]=q1.y; v[6]=q1.z; v[7]=q1.w;
    v[8]=q2.x; v[9]=q2.y; v[10]=q2.z; v[11]=q2.w;
    v[12]=q3.x; v[13]=q3.y; v[14]=q3.z; v[15]=q3.w;

    float m = v[0];
#pragma unroll
    for (int g = 1; g < NGATES; ++g) m = fmaxf(m, v[g]);
    float s = 0.f;
#pragma unroll
    for (int g = 0; g < NGATES; ++g) { v[g] = expf(v[g] - m); s += v[g]; }
    float inv = 1.0f / s;

    float c0 = 0.f, c1 = 0.f, c2 = 0.f, c3 = 0.f;
#pragma unroll
    for (int g = 0; g < NGATES; ++g) {
        c0 += v[g] * c_coeff[g][0];
        c1 += v[g] * c_coeff[g][1];
        c2 += v[g] * c_coeff[g][2];
        c3 += v[g] * c_coeff[g][3];
    }
    f16x4 h;
    h.x = (_Float16)(c0 * inv); h.y = (_Float16)(c1 * inv);
    h.z = (_Float16)(c2 * inv); h.w = (_Float16)(c3 * inv);
    Wh[j] = h;
    Ipk[j] = (unsigned)idx_a[j] | ((unsigned)idx_b[j] << 16);   // both < 16384
}

// Kernel 2: R2's streaming shape (2048 blocks x 1024 threads, 1 row/block,
// 64 KB LDS -> 2 blocks/CU) with an explicitly phase-split body for MLP:
//   A) issue stage + ALL idx/W loads (independent, drain with the barrier)
//   B) ALL 32 LDS gathers into named registers (independent ds_reads)
//   C) compute + 4 NT stores
// __launch_bounds__(1024,4) lifts the VGPR cap to 128 so phases don't spill.
__global__ __launch_bounds__(1024, 4) void logic_row_kernel(
    const float* __restrict__ x,
    const f16x8* __restrict__ Wh8,
    const uint4* __restrict__ Ipk4,
    float*       __restrict__ out)
{
    __shared__ float row[IN_DIM];   // 64 KB
    const int tid = threadIdx.x;
    const int i   = blockIdx.x;

    // --- Phase A: coalesced stage + row-invariant loads, all in flight ---
    const f32x4* xr = reinterpret_cast<const f32x4*>(x + (size_t)i * IN_DIM);
    f32x4* rr = reinterpret_cast<f32x4*>(row);
#pragma unroll
    for (int k = 0; k < 4; ++k) rr[tid + k * 1024] = xr[tid + k * 1024];

    uint4 q[4];
    f16x8 w[8];                       // w[2k],w[2k+1] cover outputs of group k
#pragma unroll
    for (int k = 0; k < 4; ++k) {
        q[k]       = Ipk4[tid + k * 1024];
        w[2*k]     = Wh8[(size_t)(tid + k * 1024) * 2];
        w[2*k + 1] = Wh8[(size_t)(tid + k * 1024) * 2 + 1];
    }

    __syncthreads();                  // drains stage + A-loads, row visible

    // --- Phase B: all 32 gathers, no consumer in between ---
    float av[16], bv[16];
#pragma unroll
    for (int k = 0; k < 4; ++k) {
        av[4*k+0] = row[q[k].x & 0xFFFFu];  bv[4*k+0] = row[q[k].x >> 16];
        av[4*k+1] = row[q[k].y & 0xFFFFu];  bv[4*k+1] = row[q[k].y >> 16];
        av[4*k+2] = row[q[k].z & 0xFFFFu];  bv[4*k+2] = row[q[k].z >> 16];
        av[4*k+3] = row[q[k].w & 0xFFFFu];  bv[4*k+3] = row[q[k].w >> 16];
    }

    // --- Phase C: compute + NT stores ---
    f32x4* o4 = reinterpret_cast<f32x4*>(out + (size_t)i * OUT_DIM);
#pragma unroll
    for (int k = 0; k < 4; ++k) {
        f16x8 wa = w[2*k], wb = w[2*k + 1];
        float a0 = av[4*k+0], b0 = bv[4*k+0];
        float a1 = av[4*k+1], b1 = bv[4*k+1];
        float a2 = av[4*k+2], b2 = bv[4*k+2];
        float a3 = av[4*k+3], b3 = bv[4*k+3];

        f32x4 res;
        res.x = (float)wa[0] + (float)wa[1] * a0 + (float)wa[2] * b0 + (float)wa[3] * (a0 * b0);
        res.y = (float)wa[4] + (float)wa[5] * a1 + (float)wa[6] * b1 + (float)wa[7] * (a1 * b1);
        res.z = (float)wb[0] + (float)wb[1] * a2 + (float)wb[2] * b2 + (float)wb[3] * (a2 * b2);
        res.w = (float)wb[4] + (float)wb[5] * a3 + (float)wb[6] * b3 + (float)wb[7] * (a3 * b3);
        __builtin_nontemporal_store(res, &o4[tid + k * 1024]);
    }
}

extern "C" void kernel_launch(void* const* d_in, const int* in_sizes, int n_in,
                              void* d_out, int out_size, void* d_ws, size_t ws_size,
                              hipStream_t stream) {
    const float* x       = (const float*)d_in[0];
    const float* weights = (const float*)d_in[1];
    const int*   idx_a   = (const int*)d_in[2];
    const int*   idx_b   = (const int*)d_in[3];
    float* out = (float*)d_out;

    // Workspace layout: Wh (OUT_DIM f16x4 = 128 KB), Ipk (OUT_DIM uint = 64 KB)
    f16x4*    Wh  = (f16x4*)d_ws;
    unsigned* Ipk = (unsigned*)((char*)d_ws + (size_t)OUT_DIM * sizeof(f16x4));

    prep_kernel<<<(OUT_DIM + 255) / 256, 256, 0, stream>>>(weights, idx_a, idx_b, Wh, Ipk);
    logic_row_kernel<<<BATCH, 1024, 0, stream>>>(x, (const f16x8*)Wh, (const uint4*)Ipk, out);
}

// Round 7
// 49.285 us; speedup vs baseline: 2.2357x; 1.1416x over previous
//
#include <hip/hip_runtime.h>

#define BATCH   2048
#define IN_DIM  16384
#define OUT_DIM 16384
#define NGATES  16

typedef float    f32x4 __attribute__((ext_vector_type(4)));
typedef _Float16 f16x4 __attribute__((ext_vector_type(4)));
typedef _Float16 f16x8 __attribute__((ext_vector_type(8)));

// COEFF[16][4] from the reference, hard-coded.
__constant__ float c_coeff[NGATES][4] = {
    {0, 0, 0, 0},  {0, 0, 0, 1},  {0, 1, 0, -1}, {0, 1, 0, 0},
    {0, 0, 1, -1}, {0, 0, 1, 0},  {0, 1, 1, -2}, {0, 1, 1, -1},
    {1, -1, -1, 1},{1, -1, -1, 2},{1, 0, -1, 0}, {1, 0, -1, 1},
    {1, -1, 0, 0}, {1, -1, 0, 1}, {1, 0, 0, -1}, {1, 0, 0, 0}
};

// Kernel 1: per output column j, fold softmax(weights[j,:]) @ COEFF into
// W[j] stored as f16x4 (8 B), and pack gather indices into one uint32.
__global__ __launch_bounds__(256) void prep_kernel(
    const float* __restrict__ weights,
    const int*   __restrict__ idx_a,
    const int*   __restrict__ idx_b,
    f16x4*       __restrict__ Wh,
    unsigned*    __restrict__ Ipk)
{
    int j = blockIdx.x * blockDim.x + threadIdx.x;
    if (j >= OUT_DIM) return;

    const float4* wrow = reinterpret_cast<const float4*>(weights + (size_t)j * NGATES);
    float v[NGATES];
    float4 q0 = wrow[0], q1 = wrow[1], q2 = wrow[2], q3 = wrow[3];
    v[0]=q0.x; v[1]=q0.y; v[2]=q0.z; v[3]=q0.w;
    v[4]=q1.x; v[5]=q1.y; v[6]=q1.z; v[7]=q1.w;
    v[8]=q2.x; v[9]=q2.y; v[10]=q2.z; v[11]=q2.w;
    v[12]=q3.x; v[13]=q3.y; v[14]=q3.z; v[15]=q3.w;

    float m = v[0];
#pragma unroll
    for (int g = 1; g < NGATES; ++g) m = fmaxf(m, v[g]);
    float s = 0.f;
#pragma unroll
    for (int g = 0; g < NGATES; ++g) { v[g] = expf(v[g] - m); s += v[g]; }
    float inv = 1.0f / s;

    float c0 = 0.f, c1 = 0.f, c2 = 0.f, c3 = 0.f;
#pragma unroll
    for (int g = 0; g < NGATES; ++g) {
        c0 += v[g] * c_coeff[g][0];
        c1 += v[g] * c_coeff[g][1];
        c2 += v[g] * c_coeff[g][2];
        c3 += v[g] * c_coeff[g][3];
    }
    f16x4 h;
    h.x = (_Float16)(c0 * inv); h.y = (_Float16)(c1 * inv);
    h.z = (_Float16)(c2 * inv); h.w = (_Float16)(c3 * inv);
    Wh[j] = h;
    Ipk[j] = (unsigned)idx_a[j] | ((unsigned)idx_b[j] << 16);   // both < 16384
}

// Kernel 2: 2048 blocks x 512 threads, 1 row/block. x row staged in LDS as
// f16 (32 KB) -> 4 blocks/CU resident (32 waves = full wave cap), so the
// stage+barrier phase of one block hides under the compute of three others.
// Per thread: 32 outputs in a depth-1 software-pipelined loop (prefetch next
// idx/W during current gather+compute). launch_bounds(512,8) caps VGPR at 64
// -- the R3/R4 regressions were register spills to scratch (FETCH/WRITE
// amplification); this plan fits (R5 used 40).
__global__ __launch_bounds__(512, 8) void logic_row_kernel(
    const float* __restrict__ x,
    const f16x8* __restrict__ Wh8,
    const uint4* __restrict__ Ipk4,
    float*       __restrict__ out)
{
    __shared__ _Float16 rowh[IN_DIM];   // 32 KB
    const int tid = threadIdx.x;
    const int i   = blockIdx.x;

    // --- Stage: f32x4 coalesced load -> f16x4 -> LDS (8 B/thread/chunk) ---
    const f32x4* xr  = reinterpret_cast<const f32x4*>(x + (size_t)i * IN_DIM);
    f16x4*       rhw = reinterpret_cast<f16x4*>(rowh);
#pragma unroll
    for (int k = 0; k < IN_DIM / 4 / 512; ++k) {      // 8 chunks
        f32x4 v = xr[tid + k * 512];
        f16x4 h;
        h.x = (_Float16)v.x; h.y = (_Float16)v.y;
        h.z = (_Float16)v.z; h.w = (_Float16)v.w;
        rhw[tid + k * 512] = h;
    }

    // Prefetch first group's idx/W before the barrier (L2 latency hides
    // under the stage drain).
    uint4 qc = Ipk4[tid];
    f16x8 wa = Wh8[(size_t)tid * 2];
    f16x8 wb = Wh8[(size_t)tid * 2 + 1];

    __syncthreads();

    f32x4* o4 = reinterpret_cast<f32x4*>(out + (size_t)i * OUT_DIM);

    for (int k = 0; k < OUT_DIM / 4 / 512; ++k) {     // 8 groups of 4 outputs
        // Prefetch next group's row-invariant data (independent of compute).
        uint4 qn;  f16x8 wan, wbn;
        if (k + 1 < OUT_DIM / 4 / 512) {
            const int j4n = tid + (k + 1) * 512;
            qn  = Ipk4[j4n];
            wan = Wh8[(size_t)j4n * 2];
            wbn = Wh8[(size_t)j4n * 2 + 1];
        }

        // Gather (8 independent ds_read_u16) + compute + NT store.
        float a0 = (float)rowh[qc.x & 0xFFFFu], b0 = (float)rowh[qc.x >> 16];
        float a1 = (float)rowh[qc.y & 0xFFFFu], b1 = (float)rowh[qc.y >> 16];
        float a2 = (float)rowh[qc.z & 0xFFFFu], b2 = (float)rowh[qc.z >> 16];
        float a3 = (float)rowh[qc.w & 0xFFFFu], b3 = (float)rowh[qc.w >> 16];

        f32x4 res;
        res.x = (float)wa[0] + (float)wa[1] * a0 + (float)wa[2] * b0 + (float)wa[3] * (a0 * b0);
        res.y = (float)wa[4] + (float)wa[5] * a1 + (float)wa[6] * b1 + (float)wa[7] * (a1 * b1);
        res.z = (float)wb[0] + (float)wb[1] * a2 + (float)wb[2] * b2 + (float)wb[3] * (a2 * b2);
        res.w = (float)wb[4] + (float)wb[5] * a3 + (float)wb[6] * b3 + (float)wb[7] * (a3 * b3);
        __builtin_nontemporal_store(res, &o4[tid + k * 512]);

        qc = qn; wa = wan; wb = wbn;
    }
}

extern "C" void kernel_launch(void* const* d_in, const int* in_sizes, int n_in,
                              void* d_out, int out_size, void* d_ws, size_t ws_size,
                              hipStream_t stream) {
    const float* x       = (const float*)d_in[0];
    const float* weights = (const float*)d_in[1];
    const int*   idx_a   = (const int*)d_in[2];
    const int*   idx_b   = (const int*)d_in[3];
    float* out = (float*)d_out;

    // Workspace layout: Wh (OUT_DIM f16x4 = 128 KB), Ipk (OUT_DIM uint = 64 KB)
    f16x4*    Wh  = (f16x4*)d_ws;
    unsigned* Ipk = (unsigned*)((char*)d_ws + (size_t)OUT_DIM * sizeof(f16x4));

    prep_kernel<<<(OUT_DIM + 255) / 256, 256, 0, stream>>>(weights, idx_a, idx_b, Wh, Ipk);
    logic_row_kernel<<<BATCH, 512, 0, stream>>>(x, (const f16x8*)Wh, (const uint4*)Ipk, out);
}